// Round 9
// baseline (295.049 us; speedup 1.0000x reference)
//
#include <hip/hip_runtime.h>

// Reprojection residual. History:
//  R5: 152us (nt streams, exact grid).  R6: 138us (VMEM 20->6/thread).
//  FETCH ~429MB @3.65TB/s, VALU 17%, occ 78%. Model: miss-queue x latency
//  bound on random 64B gather lines (all L3-hits; HBM itself only 1.4TB/s).
// R8 failed on a t-component indexing bug (used t4.y/z/w from the fallback's
//  offset-by-3 window; prep stores (tx,ty,tz,0) -> must use t4.x/y/z).
// R9 = R8 with that one-line fix:
//  (1) pad pts3d 12B->16B rows in ws -- kills ~19% line-straddling gathers;
//  (2) pre-normalize + pad pose to 32B rows; (3) 4 obs/thread.

typedef int   i32x4 __attribute__((ext_vector_type(4)));
typedef float f32x4 __attribute__((ext_vector_type(4)));
typedef float f32x4a __attribute__((ext_vector_type(4), aligned(4)));
typedef int   i32x2 __attribute__((ext_vector_type(2)));

// ---- prep: normalize quaternion, pad pose rows 7 -> 8 floats ----
__global__ void prep_pose(const float* __restrict__ pose,
                          float* __restrict__ pose8, int nCams)
{
    int r = blockIdx.x * blockDim.x + threadIdx.x;
    if (r >= nCams) return;
    const float* src = pose + 7 * r;
    float qw = src[0], qx = src[1], qy = src[2], qz = src[3];
    float inv = 1.0f / sqrtf(qw*qw + qx*qx + qy*qy + qz*qz);
    f32x4 q; q.x = qw*inv; q.y = qx*inv; q.z = qy*inv; q.w = qz*inv;
    f32x4 t; t.x = src[4]; t.y = src[5]; t.z = src[6]; t.w = 0.0f;
    *(f32x4*)(pose8 + 8*r)     = q;
    *(f32x4*)(pose8 + 8*r + 4) = t;
}

// ---- prep: pad pts3d rows 12B -> 16B (aligned, never line-straddling) ----
__global__ void prep_pts(const float* __restrict__ pts3,
                         float* __restrict__ pts4, int nPts)
{
    int r = blockIdx.x * blockDim.x + threadIdx.x;
    if (r >= nPts) return;
    f32x4 v;
    v.x = pts3[3*r]; v.y = pts3[3*r + 1]; v.z = pts3[3*r + 2]; v.w = 0.0f;
    *(f32x4*)(pts4 + 4*r) = v;
}

// ---- main: 4 obs per thread, all gathers aligned 16B ----
__global__ void __launch_bounds__(256, 8)
reproj_main(const f32x4* __restrict__ p2d,     // 2 obs per vec
            const float* __restrict__ K,
            const f32x4* __restrict__ pose8,   // [2c]=q(normalized), [2c+1]=t
            const f32x4* __restrict__ pts4,    // padded points
            const i32x4* __restrict__ camIdx,  // 4 obs per vec
            const i32x4* __restrict__ ptIdx,
            f32x4*       __restrict__ out,     // 2 obs per vec
            int nQuads)
{
    int i = blockIdx.x * blockDim.x + threadIdx.x;
    if (i >= nQuads) return;

    i32x4 ci = __builtin_nontemporal_load(&camIdx[i]);
    i32x4 pi = __builtin_nontemporal_load(&ptIdx[i]);
    f32x4 pA = __builtin_nontemporal_load(&p2d[2*i]);
    f32x4 pB = __builtin_nontemporal_load(&p2d[2*i + 1]);

    float K00 = K[0], K01 = K[1], K02 = K[2];
    float K10 = K[3], K11 = K[4], K12 = K[5];
    float K20 = K[6], K21 = K[7], K22 = K[8];

    auto project = [&](int c, int pidx, float& ox, float& oy) {
        f32x4 q4 = pose8[2*c];
        f32x4 t4 = pose8[2*c + 1];   // (tx, ty, tz, 0)
        f32x4 v  = pts4[pidx];
        float qw = q4.x, qx = q4.y, qy = q4.z, qz = q4.w;
        float x = v.x, y = v.y, z = v.z;

        float uvx = 2.0f * (qy*z - qz*y);
        float uvy = 2.0f * (qz*x - qx*z);
        float uvz = 2.0f * (qx*y - qy*x);

        float rx = x + qw*uvx + (qy*uvz - qz*uvy) + t4.x;
        float ry = y + qw*uvy + (qz*uvx - qx*uvz) + t4.y;
        float rz = z + qw*uvz + (qx*uvy - qy*uvx) + t4.z;

        float px = K00*rx + K01*ry + K02*rz;
        float py = K10*rx + K11*ry + K12*rz;
        float pz = K20*rx + K21*ry + K22*rz;

        ox = px / pz;
        oy = py / pz;
    };

    float x0,y0,x1,y1,x2,y2,x3,y3;
    project(ci.x, pi.x, x0, y0);
    project(ci.y, pi.y, x1, y1);
    project(ci.z, pi.z, x2, y2);
    project(ci.w, pi.w, x3, y3);

    f32x4 rA, rB;
    rA.x = x0 - pA.x; rA.y = y0 - pA.y; rA.z = x1 - pA.z; rA.w = y1 - pA.w;
    rB.x = x2 - pB.x; rB.y = y2 - pB.y; rB.z = x3 - pB.z; rB.w = y3 - pB.w;
    __builtin_nontemporal_store(rA, &out[2*i]);
    __builtin_nontemporal_store(rB, &out[2*i + 1]);
}

// ---- fallback (ws too small): proven R6 kernel ----
__global__ void __launch_bounds__(256, 8)
reproj_fallback(const f32x4* __restrict__ p2d,
                const float* __restrict__ K,
                const float* __restrict__ pose,
                const float* __restrict__ pts3d,
                const i32x2* __restrict__ camIdx,
                const i32x2* __restrict__ ptIdx,
                f32x4*       __restrict__ out,
                int nPairs, int nPts)
{
    int i = blockIdx.x * blockDim.x + threadIdx.x;
    if (i >= nPairs) return;

    i32x2 ci = __builtin_nontemporal_load(&camIdx[i]);
    i32x2 pi = __builtin_nontemporal_load(&ptIdx[i]);
    f32x4 p  = __builtin_nontemporal_load(&p2d[i]);

    float K00 = K[0], K01 = K[1], K02 = K[2];
    float K10 = K[3], K11 = K[4], K12 = K[5];
    float K20 = K[6], K21 = K[7], K22 = K[8];

    auto project = [&](int c, int pidx, float& ox, float& oy) {
        f32x4 q4 = *(const f32x4a*)(pose + 7*c);       // qw qx qy qz
        f32x4 t4 = *(const f32x4a*)(pose + 7*c + 3);   // qz tx ty tz
        float qw = q4.x, qx = q4.y, qy = q4.z, qz = q4.w;
        float tx = t4.y, ty = t4.z, tz = t4.w;

        float inv = 1.0f / sqrtf(qw*qw + qx*qx + qy*qy + qz*qz);
        qw *= inv; qx *= inv; qy *= inv; qz *= inv;

        float x, y, z;
        if (pidx < nPts - 1) {
            f32x4 v = *(const f32x4a*)(pts3d + 3*pidx);
            x = v.x; y = v.y; z = v.z;
        } else {
            f32x4 v = *(const f32x4a*)(pts3d + 3*pidx - 1);
            x = v.y; y = v.z; z = v.w;
        }

        float uvx = 2.0f * (qy*z - qz*y);
        float uvy = 2.0f * (qz*x - qx*z);
        float uvz = 2.0f * (qx*y - qy*x);

        float rx = x + qw*uvx + (qy*uvz - qz*uvy) + tx;
        float ry = y + qw*uvy + (qz*uvx - qx*uvz) + ty;
        float rz = z + qw*uvz + (qx*uvy - qy*uvx) + tz;

        float px = K00*rx + K01*ry + K02*rz;
        float py = K10*rx + K11*ry + K12*rz;
        float pz = K20*rx + K21*ry + K22*rz;

        ox = px / pz;
        oy = py / pz;
    };

    float ax, ay, bx, by;
    project(ci.x, pi.x, ax, ay);
    project(ci.y, pi.y, bx, by);

    f32x4 r;
    r.x = ax - p.x; r.y = ay - p.y; r.z = bx - p.z; r.w = by - p.w;
    __builtin_nontemporal_store(r, &out[i]);
}

extern "C" void kernel_launch(void* const* d_in, const int* in_sizes, int n_in,
                              void* d_out, int out_size, void* d_ws, size_t ws_size,
                              hipStream_t stream)
{
    const float* points_2d = (const float*)d_in[0];   // (N_OBS, 2) f32
    const float* K         = (const float*)d_in[1];   // (3,3) f32
    const float* pose      = (const float*)d_in[2];   // (N_CAMS, 7) f32
    const float* points_3d = (const float*)d_in[3];   // (N_PTS, 3) f32
    const int*   camIdx    = (const int*)d_in[4];     // (N_OBS,) i32
    const int*   ptIdx    = (const int*)d_in[5];      // (N_OBS,) i32
    float*       out       = (float*)d_out;           // (N_OBS, 2) f32

    int nObs  = in_sizes[4];            // 8,000,000
    int nCams = in_sizes[2] / 7;        // 2,000
    int nPts  = in_sizes[3] / 3;        // 1,000,000

    // ws layout: [0, 64KB) pose8 ; [64KB, 64KB+16MB) pts4
    size_t poseBytes = (size_t)nCams * 8 * sizeof(float);
    size_t ptsOff    = 65536;
    size_t needed    = ptsOff + (size_t)nPts * 4 * sizeof(float);

    const int block = 256;

    if (ws_size >= needed && nObs % 4 == 0 && poseBytes <= ptsOff) {
        float* pose8 = (float*)d_ws;
        float* pts4  = (float*)((char*)d_ws + ptsOff);

        prep_pose<<<(nCams + block - 1) / block, block, 0, stream>>>(pose, pose8, nCams);
        prep_pts<<<(nPts + block - 1) / block, block, 0, stream>>>(points_3d, pts4, nPts);

        int nQuads = nObs / 4;          // 2,000,000
        int grid = (nQuads + block - 1) / block;
        reproj_main<<<grid, block, 0, stream>>>(
            (const f32x4*)points_2d, K, (const f32x4*)pose8, (const f32x4*)pts4,
            (const i32x4*)camIdx, (const i32x4*)ptIdx,
            (f32x4*)out, nQuads);
    } else {
        int nPairs = nObs / 2;
        int grid = (nPairs + block - 1) / block;
        reproj_fallback<<<grid, block, 0, stream>>>(
            (const f32x4*)points_2d, K, pose, points_3d,
            (const i32x2*)camIdx, (const i32x2*)ptIdx,
            (f32x4*)out, nPairs, nPts);
    }
}

// Round 10
// 267.758 us; speedup vs baseline: 1.1019x; 1.1019x over previous
//
#include <hip/hip_runtime.h>

// Reprojection residual. Measured history (main kernel dispatch):
//  R2 172us | R5 152us (nt+exact grid) | R6 138us (VMEM 20->6) |
//  R9 155us (16B-padded table REGRESSED: footprint 12->16MB cut L2 hit rate;
//            VALU 16.8->9.4% with no speedup -> VALU not the constraint).
// Both R6/R9 saturate ~3.65-3.7 TB/s on the L2-miss path -> fabric ceiling
// for random-line+stream mix. R10: R6 structure (12MB unpadded table,
// 2 obs/thread) + tiny prep_pose (normalized, 32B rows, 64KB resident) to
// isolate the pose path. If >=135us -> structural roofline.

typedef int   i32x2 __attribute__((ext_vector_type(2)));
typedef float f32x4 __attribute__((ext_vector_type(4)));
typedef float f32x4a __attribute__((ext_vector_type(4), aligned(4)));

// ---- prep: normalize quaternion, pad pose rows 7 -> 8 floats ----
__global__ void prep_pose(const float* __restrict__ pose,
                          float* __restrict__ pose8, int nCams)
{
    int r = blockIdx.x * blockDim.x + threadIdx.x;
    if (r >= nCams) return;
    const float* src = pose + 7 * r;
    float qw = src[0], qx = src[1], qy = src[2], qz = src[3];
    float inv = 1.0f / sqrtf(qw*qw + qx*qx + qy*qy + qz*qz);
    f32x4 q; q.x = qw*inv; q.y = qx*inv; q.z = qy*inv; q.w = qz*inv;
    f32x4 t; t.x = src[4]; t.y = src[5]; t.z = src[6]; t.w = 0.0f;
    *(f32x4*)(pose8 + 8*r)     = q;
    *(f32x4*)(pose8 + 8*r + 4) = t;
}

// ---- main: 2 obs/thread, unpadded 12B point rows (12MB table) ----
__global__ void __launch_bounds__(256, 8)
reproj_main(const f32x4* __restrict__ p2d,     // 2 obs per vec
            const float* __restrict__ K,
            const f32x4* __restrict__ pose8,   // [2c]=q(normalized), [2c+1]=(t,0)
            const float* __restrict__ pts3d,   // (1e6,3) original
            const i32x2* __restrict__ camIdx,
            const i32x2* __restrict__ ptIdx,
            f32x4*       __restrict__ out,
            int nPairs, int nPts)
{
    int i = blockIdx.x * blockDim.x + threadIdx.x;
    if (i >= nPairs) return;

    i32x2 ci = __builtin_nontemporal_load(&camIdx[i]);
    i32x2 pi = __builtin_nontemporal_load(&ptIdx[i]);
    f32x4 p  = __builtin_nontemporal_load(&p2d[i]);

    float K00 = K[0], K01 = K[1], K02 = K[2];
    float K10 = K[3], K11 = K[4], K12 = K[5];
    float K20 = K[6], K21 = K[7], K22 = K[8];

    auto project = [&](int c, int pidx, float& ox, float& oy) {
        f32x4 q4 = pose8[2*c];       // qw qx qy qz (normalized)
        f32x4 t4 = pose8[2*c + 1];   // tx ty tz 0
        float qw = q4.x, qx = q4.y, qy = q4.z, qz = q4.w;

        // point row = 12B; one 16B load. Last row: shift window -4B.
        float x, y, z;
        if (pidx < nPts - 1) {
            f32x4 v = *(const f32x4a*)(pts3d + 3*pidx);
            x = v.x; y = v.y; z = v.z;
        } else {
            f32x4 v = *(const f32x4a*)(pts3d + 3*pidx - 1);
            x = v.y; y = v.z; z = v.w;
        }

        float uvx = 2.0f * (qy*z - qz*y);
        float uvy = 2.0f * (qz*x - qx*z);
        float uvz = 2.0f * (qx*y - qy*x);

        float rx = x + qw*uvx + (qy*uvz - qz*uvy) + t4.x;
        float ry = y + qw*uvy + (qz*uvx - qx*uvz) + t4.y;
        float rz = z + qw*uvz + (qx*uvy - qy*uvx) + t4.z;

        float px = K00*rx + K01*ry + K02*rz;
        float py = K10*rx + K11*ry + K12*rz;
        float pz = K20*rx + K21*ry + K22*rz;

        ox = px / pz;
        oy = py / pz;
    };

    float ax, ay, bx, by;
    project(ci.x, pi.x, ax, ay);
    project(ci.y, pi.y, bx, by);

    f32x4 r;
    r.x = ax - p.x; r.y = ay - p.y; r.z = bx - p.z; r.w = by - p.w;
    __builtin_nontemporal_store(r, &out[i]);
}

// ---- fallback (ws too small): proven R6 kernel, self-contained ----
__global__ void __launch_bounds__(256, 8)
reproj_fallback(const f32x4* __restrict__ p2d,
                const float* __restrict__ K,
                const float* __restrict__ pose,
                const float* __restrict__ pts3d,
                const i32x2* __restrict__ camIdx,
                const i32x2* __restrict__ ptIdx,
                f32x4*       __restrict__ out,
                int nPairs, int nPts)
{
    int i = blockIdx.x * blockDim.x + threadIdx.x;
    if (i >= nPairs) return;

    i32x2 ci = __builtin_nontemporal_load(&camIdx[i]);
    i32x2 pi = __builtin_nontemporal_load(&ptIdx[i]);
    f32x4 p  = __builtin_nontemporal_load(&p2d[i]);

    float K00 = K[0], K01 = K[1], K02 = K[2];
    float K10 = K[3], K11 = K[4], K12 = K[5];
    float K20 = K[6], K21 = K[7], K22 = K[8];

    auto project = [&](int c, int pidx, float& ox, float& oy) {
        f32x4 q4 = *(const f32x4a*)(pose + 7*c);       // qw qx qy qz
        f32x4 t4 = *(const f32x4a*)(pose + 7*c + 3);   // qz tx ty tz
        float qw = q4.x, qx = q4.y, qy = q4.z, qz = q4.w;
        float tx = t4.y, ty = t4.z, tz = t4.w;

        float inv = 1.0f / sqrtf(qw*qw + qx*qx + qy*qy + qz*qz);
        qw *= inv; qx *= inv; qy *= inv; qz *= inv;

        float x, y, z;
        if (pidx < nPts - 1) {
            f32x4 v = *(const f32x4a*)(pts3d + 3*pidx);
            x = v.x; y = v.y; z = v.z;
        } else {
            f32x4 v = *(const f32x4a*)(pts3d + 3*pidx - 1);
            x = v.y; y = v.z; z = v.w;
        }

        float uvx = 2.0f * (qy*z - qz*y);
        float uvy = 2.0f * (qz*x - qx*z);
        float uvz = 2.0f * (qx*y - qy*x);

        float rx = x + qw*uvx + (qy*uvz - qz*uvy) + tx;
        float ry = y + qw*uvy + (qz*uvx - qx*uvz) + ty;
        float rz = z + qw*uvz + (qx*uvy - qy*uvx) + tz;

        float px = K00*rx + K01*ry + K02*rz;
        float py = K10*rx + K11*ry + K12*rz;
        float pz = K20*rx + K21*ry + K22*rz;

        ox = px / pz;
        oy = py / pz;
    };

    float ax, ay, bx, by;
    project(ci.x, pi.x, ax, ay);
    project(ci.y, pi.y, bx, by);

    f32x4 r;
    r.x = ax - p.x; r.y = ay - p.y; r.z = bx - p.z; r.w = by - p.w;
    __builtin_nontemporal_store(r, &out[i]);
}

extern "C" void kernel_launch(void* const* d_in, const int* in_sizes, int n_in,
                              void* d_out, int out_size, void* d_ws, size_t ws_size,
                              hipStream_t stream)
{
    const float* points_2d = (const float*)d_in[0];   // (N_OBS, 2) f32
    const float* K         = (const float*)d_in[1];   // (3,3) f32
    const float* pose      = (const float*)d_in[2];   // (N_CAMS, 7) f32
    const float* points_3d = (const float*)d_in[3];   // (N_PTS, 3) f32
    const int*   camIdx    = (const int*)d_in[4];     // (N_OBS,) i32
    const int*   ptIdx     = (const int*)d_in[5];     // (N_OBS,) i32
    float*       out       = (float*)d_out;           // (N_OBS, 2) f32

    int nObs  = in_sizes[4];            // 8,000,000
    int nCams = in_sizes[2] / 7;        // 2,000
    int nPts  = in_sizes[3] / 3;        // 1,000,000
    int nPairs = nObs / 2;

    size_t poseBytes = (size_t)nCams * 8 * sizeof(float);   // 64KB

    const int block = 256;
    int grid = (nPairs + block - 1) / block;

    if (ws_size >= poseBytes && nObs % 2 == 0) {
        float* pose8 = (float*)d_ws;
        prep_pose<<<(nCams + block - 1) / block, block, 0, stream>>>(pose, pose8, nCams);
        reproj_main<<<grid, block, 0, stream>>>(
            (const f32x4*)points_2d, K, (const f32x4*)pose8, points_3d,
            (const i32x2*)camIdx, (const i32x2*)ptIdx,
            (f32x4*)out, nPairs, nPts);
    } else {
        reproj_fallback<<<grid, block, 0, stream>>>(
            (const f32x4*)points_2d, K, pose, points_3d,
            (const i32x2*)camIdx, (const i32x2*)ptIdx,
            (f32x4*)out, nPairs, nPts);
    }
}